// Round 2
// baseline (309.691 us; speedup 1.0000x reference)
//
#include <hip/hip_runtime.h>
#include <hip/hip_bf16.h>
#include <hip/hip_fp16.h>

typedef _Float16 half8 __attribute__((ext_vector_type(8)));
typedef float floatx4 __attribute__((ext_vector_type(4)));
typedef unsigned short u16;
typedef unsigned int u32;
typedef unsigned long long u64;

#define LEAKY 0.2f
#define MASKV -9.0e15f

// ---------------- Kernel A: h_ds[b][d] = (mean of 150 rows) @ wd ----------------
__global__ __launch_bounds__(128) void k_hds(const float* __restrict__ hl,
                                             const float* __restrict__ ht,
                                             const float* __restrict__ ie,
                                             const float* __restrict__ wd,
                                             float* __restrict__ hds) {
  int b = blockIdx.x, d = threadIdx.x;
  const size_t base = (size_t)b * 50 * 128 + d;
  float acc = 0.f;
  for (int l2 = 0; l2 < 50; ++l2) {
    size_t o = base + (size_t)l2 * 128;
    acc += hl[o] + ht[o] + ie[o];
  }
  __shared__ float ml[128];
  ml[d] = acc * (1.0f / 150.0f);
  __syncthreads();
  float o = 0.f;
  for (int k = 0; k < 128; ++k) o = fmaf(ml[k], wd[k * 128 + d], o);
  hds[b * 128 + d] = o;
}

// ---------------- Kernel B: s[w][b][i], h16[b][i][d], h16T[b][d][i] ----------------
__global__ __launch_bounds__(256) void k_prep(const float* __restrict__ h,
                                              const float* __restrict__ hds,
                                              const float* __restrict__ a0,
                                              const float* __restrict__ a1,
                                              const float* __restrict__ a2,
                                              const float* __restrict__ a3,
                                              float* __restrict__ s,
                                              u16* __restrict__ h16,
                                              u16* __restrict__ h16T) {
  int b = blockIdx.x >> 3, i0 = (blockIdx.x & 7) * 64;
  int tid = threadIdx.x, w = tid >> 6, l = tid & 63;
  __shared__ u16 tile[64][130];  // +2 pad: conflict-free column reads
  int d0 = 2 * l;
  float2 hd2 = *(const float2*)(hds + b * 128 + d0);
  float2 av0 = *(const float2*)(a0 + d0);
  float2 av1 = *(const float2*)(a1 + d0);
  float2 av2 = *(const float2*)(a2 + d0);
  float2 av3 = *(const float2*)(a3 + d0);
  for (int rr = 0; rr < 16; ++rr) {
    int il = rr * 4 + w;
    size_t row = (size_t)b * 512 + i0 + il;
    float2 hv = *(const float2*)(h + row * 128 + d0);
    _Float16 f0 = (_Float16)hv.x, f1 = (_Float16)hv.y;
    u16 u0 = __builtin_bit_cast(u16, f0), u1 = __builtin_bit_cast(u16, f1);
    tile[il][d0] = u0;
    tile[il][d0 + 1] = u1;
    *(u32*)(h16 + row * 128 + d0) = (u32)u0 | ((u32)u1 << 16);
    float t0 = hv.x * hd2.x, t1 = hv.y * hd2.y;
    float p0 = t0 * av0.x + t1 * av0.y;
    float p1 = t0 * av1.x + t1 * av1.y;
    float p2 = t0 * av2.x + t1 * av2.y;
    float p3 = t0 * av3.x + t1 * av3.y;
    for (int off = 32; off >= 1; off >>= 1) {
      p0 += __shfl_xor(p0, off);
      p1 += __shfl_xor(p1, off);
      p2 += __shfl_xor(p2, off);
      p3 += __shfl_xor(p3, off);
    }
    if (l < 4) {
      float pw = (l == 0) ? p0 : (l == 1) ? p1 : (l == 2) ? p2 : p3;
      s[((size_t)l * 64 + b) * 512 + i0 + il] = pw;
    }
  }
  __syncthreads();
  int d = tid >> 1, hf = tid & 1;
  u32 wds[16];
#pragma unroll
  for (int k = 0; k < 16; ++k) {
    u32 lo = tile[32 * hf + 2 * k][d];
    u32 hi = tile[32 * hf + 2 * k + 1][d];
    wds[k] = lo | (hi << 16);
  }
  uint4* dst = (uint4*)(h16T + ((size_t)b * 128 + d) * 512 + i0 + 32 * hf);
  dst[0] = make_uint4(wds[0], wds[1], wds[2], wds[3]);
  dst[1] = make_uint4(wds[4], wds[5], wds[6], wds[7]);
  dst[2] = make_uint4(wds[8], wds[9], wds[10], wds[11]);
  dst[3] = make_uint4(wds[12], wds[13], wds[14], wds[15]);
}

// ---------------- Kernel B2: adj -> per-head bitmasks ----------------
// mask[((b*4 + w)*512 + i)*8 + jw] : bit c = (adj[b][i][jw*64+c] == w+1)
__global__ __launch_bounds__(256) void k_mask(const int* __restrict__ adj,
                                              u64* __restrict__ mask) {
  int row = blockIdx.x * 4 + (threadIdx.x >> 6);  // [0, 64*512)
  int l = threadIdx.x & 63;
  int b = row >> 9, i = row & 511;
  const int* ap = adj + (size_t)row * 512;
#pragma unroll
  for (int g = 0; g < 8; ++g) {
    int av = ap[g * 64 + l];
    u64 m0 = __ballot(av == 1);
    u64 m1 = __ballot(av == 2);
    u64 m2 = __ballot(av == 3);
    u64 m3 = __ballot(av == 4);
    if (l == 0) mask[(((size_t)b * 4 + 0) * 512 + i) * 8 + g] = m0;
    if (l == 1) mask[(((size_t)b * 4 + 1) * 512 + i) * 8 + g] = m1;
    if (l == 2) mask[(((size_t)b * 4 + 2) * 512 + i) * 8 + g] = m2;
    if (l == 3) mask[(((size_t)b * 4 + 3) * 512 + i) * 8 + g] = m3;
  }
}

// ---------------- Kernel C: fused 4-head QK + select + online softmax + PV ----------------
__global__ __launch_bounds__(256, 3) void k_attn(const float* __restrict__ h,
                                                 const u16* __restrict__ h16,
                                                 const u16* __restrict__ h16T,
                                                 const float* __restrict__ s,
                                                 const u64* __restrict__ mask,
                                                 const float* __restrict__ a0,
                                                 const float* __restrict__ a1,
                                                 const float* __restrict__ a2,
                                                 const float* __restrict__ a3,
                                                 float* __restrict__ out) {
  int bid = blockIdx.x;
  int wg = (bid & 7) * 128 + (bid >> 3);  // XCD swizzle: same-b tiles share an XCD
  int b = wg >> 4, i0 = (wg & 15) * 32;
  int tid = threadIdx.x, w = tid >> 6, l = tid & 63;
  int l15 = l & 15, l4 = l >> 4;

  __shared__ u16 Kj[64 * 128];    // [j][d] f16, 16B-chunk XOR swizzled
  __shared__ u16 KjT[128 * 64];   // [d][j] f16, swizzled
  __shared__ float sel[32 * 64];  // merged logits, 16B-chunk swizzle: c4 ^ (r&15)
  __shared__ u64 msk[4][32][8];   // per-head row masks for this i-tile

  const float* aw = (w == 0) ? a0 : (w == 1) ? a1 : (w == 2) ? a2 : a3;

  // Q fragments (head w): row = l15, k = ks*32 + 8*l4 + e
  half8 qf[2][4];
#pragma unroll
  for (int R = 0; R < 2; ++R) {
    int r = 16 * R + l15;
    const float* hp = h + ((size_t)b * 512 + i0 + r) * 128;
#pragma unroll
    for (int ks = 0; ks < 4; ++ks) {
      int db = ks * 32 + l4 * 8;
      float4 h0 = *(const float4*)(hp + db);
      float4 h1 = *(const float4*)(hp + db + 4);
      float4 A0 = *(const float4*)(aw + db);
      float4 A1 = *(const float4*)(aw + db + 4);
      half8 q;
      q[0] = (_Float16)(h0.x * A0.x); q[1] = (_Float16)(h0.y * A0.y);
      q[2] = (_Float16)(h0.z * A0.z); q[3] = (_Float16)(h0.w * A0.w);
      q[4] = (_Float16)(h1.x * A1.x); q[5] = (_Float16)(h1.y * A1.y);
      q[6] = (_Float16)(h1.z * A1.z); q[7] = (_Float16)(h1.w * A1.w);
      qf[R][ks] = q;
    }
  }
  // s_i (head w), C-frag rows
  float si[2][4];
#pragma unroll
  for (int R = 0; R < 2; ++R)
#pragma unroll
    for (int e = 0; e < 4; ++e)
      si[R][e] = s[((size_t)w * 64 + b) * 512 + i0 + 16 * R + 4 * l4 + e];

  const size_t hb16 = (size_t)b * 512 * 128;
  const size_t hTb = (size_t)b * 128 * 512;

  // mask tile -> LDS (layouts match: straight copy, 2KB per head)
  {
    const u64* mp = mask + (((size_t)b * 4 + w) * 512 + i0) * 8;
    uint4* dstm = (uint4*)(&msk[w][0][0]);
    dstm[l * 2 + 0] = ((const uint4*)mp)[l * 2 + 0];
    dstm[l * 2 + 1] = ((const uint4*)mp)[l * 2 + 1];
  }
  // stage tile 0 + init sel
#pragma unroll
  for (int p = 0; p < 4; ++p) {
    int cid = p * 256 + tid;
    int j = cid >> 4, cl = cid & 15;
    uint4 v = *(const uint4*)(h16 + hb16 + (size_t)j * 128 + cl * 8);
    *(uint4*)((char*)Kj + (size_t)(j * 16 + (cl ^ (j & 15))) * 16) = v;
  }
#pragma unroll
  for (int p = 0; p < 4; ++p) {
    int cid = p * 256 + tid;
    int d = cid >> 3, cl = cid & 7;
    uint4 v = *(const uint4*)(h16T + hTb + (size_t)d * 512 + cl * 8);
    *(uint4*)((char*)KjT + (size_t)(d * 8 + (cl ^ (d & 7))) * 16) = v;
  }
  {
    float4 mv = make_float4(MASKV, MASKV, MASKV, MASKV);
    *(float4*)(sel + tid * 8) = mv;
    *(float4*)(sel + tid * 8 + 4) = mv;
  }
  __syncthreads();

  float mr[2] = {-__builtin_inff(), -__builtin_inff()};
  float lr[2] = {0.f, 0.f};
  floatx4 pv[2][2];
#pragma unroll
  for (int R = 0; R < 2; ++R)
#pragma unroll
    for (int C = 0; C < 2; ++C) pv[R][C] = (floatx4){0.f, 0.f, 0.f, 0.f};

  for (int jt = 0; jt < 8; ++jt) {
    int j0 = jt * 64;
    // ---- A: prefetch next tile into regs; fetch mask words + s_j ----
    uint4 kreg[4], treg[4];
    if (jt < 7) {
      int j0n = j0 + 64;
#pragma unroll
      for (int p = 0; p < 4; ++p) {
        int cid = p * 256 + tid;
        int j = cid >> 4, cl = cid & 15;
        kreg[p] = *(const uint4*)(h16 + hb16 + (size_t)(j0n + j) * 128 + cl * 8);
      }
#pragma unroll
      for (int p = 0; p < 4; ++p) {
        int cid = p * 256 + tid;
        int d = cid >> 3, cl = cid & 7;
        treg[p] = *(const uint4*)(h16T + hTb + (size_t)d * 512 + j0n + cl * 8);
      }
    }
    u64 mw[8];
#pragma unroll
    for (int k = 0; k < 8; ++k) {
      int r = 16 * (k >> 2) + 4 * l4 + (k & 3);
      mw[k] = msk[w][r][jt];
    }
    float sj[4];
#pragma unroll
    for (int C = 0; C < 4; ++C)
      sj[C] = s[((size_t)w * 64 + b) * 512 + j0 + 16 * C + l15];

    // ---- B: QK^T (head w) ----
    floatx4 qk[2][4];
#pragma unroll
    for (int R = 0; R < 2; ++R)
#pragma unroll
      for (int C = 0; C < 4; ++C) qk[R][C] = (floatx4){0.f, 0.f, 0.f, 0.f};
#pragma unroll
    for (int ks = 0; ks < 4; ++ks) {
      half8 bf[4];
#pragma unroll
      for (int C = 0; C < 4; ++C) {
        int j = 16 * C + l15;
        int ch = ks * 4 + l4;
        bf[C] = *(const half8*)((char*)Kj + (size_t)(j * 16 + (ch ^ (j & 15))) * 16);
      }
#pragma unroll
      for (int R = 0; R < 2; ++R)
#pragma unroll
        for (int C = 0; C < 4; ++C)
          qk[R][C] = __builtin_amdgcn_mfma_f32_16x16x32_f16(qf[R][ks], bf[C], qk[R][C], 0, 0, 0);
    }
    // ---- C: select via bitmask, write merged logits ----
#pragma unroll
    for (int C = 0; C < 4; ++C) {
#pragma unroll
      for (int R = 0; R < 2; ++R) {
#pragma unroll
        for (int e = 0; e < 4; ++e) {
          int k = R * 4 + e;
          u32 hlf = (C < 2) ? (u32)mw[k] : (u32)(mw[k] >> 32);
          if ((hlf >> (16 * (C & 1) + l15)) & 1) {
            float x = qk[R][C][e] + si[R][e] + sj[C];
            x = (x > 0.f) ? x : LEAKY * x;
            int r = 16 * R + 4 * l4 + e;
            int sw = (4 * C + (l15 >> 2)) ^ (r & 15);
            sel[r * 64 + sw * 4 + (l15 & 3)] = x;
          }
        }
      }
    }
    __syncthreads();  // B1: sel merged

    // ---- D: in-register online softmax (per-wave, redundant) ----
    float sc[2];
    half8 paf[2][2];
#pragma unroll
    for (int R = 0; R < 2; ++R) {
      int r = 16 * R + l15;
      int swa0 = (2 * l4) ^ l15;
      int swa1 = (8 + 2 * l4) ^ l15;
      float4 v0 = *(float4*)(sel + r * 64 + swa0 * 4);
      float4 v1 = *(float4*)(sel + r * 64 + (swa0 ^ 1) * 4);
      float4 v2 = *(float4*)(sel + r * 64 + swa1 * 4);
      float4 v3 = *(float4*)(sel + r * 64 + (swa1 ^ 1) * 4);
      float tmax = fmaxf(
          fmaxf(fmaxf(fmaxf(v0.x, v0.y), fmaxf(v0.z, v0.w)),
                fmaxf(fmaxf(v1.x, v1.y), fmaxf(v1.z, v1.w))),
          fmaxf(fmaxf(fmaxf(v2.x, v2.y), fmaxf(v2.z, v2.w)),
                fmaxf(fmaxf(v3.x, v3.y), fmaxf(v3.z, v3.w))));
      tmax = fmaxf(tmax, __shfl_xor(tmax, 16));
      tmax = fmaxf(tmax, __shfl_xor(tmax, 32));
      float mo = mr[R], mn = fmaxf(mo, tmax);
      sc[R] = __expf(mo - mn);
      float p0 = __expf(v0.x - mn), p1 = __expf(v0.y - mn);
      float p2 = __expf(v0.z - mn), p3 = __expf(v0.w - mn);
      float p4 = __expf(v1.x - mn), p5 = __expf(v1.y - mn);
      float p6 = __expf(v1.z - mn), p7 = __expf(v1.w - mn);
      float p8 = __expf(v2.x - mn), p9 = __expf(v2.y - mn);
      float pa = __expf(v2.z - mn), pb = __expf(v2.w - mn);
      float pc = __expf(v3.x - mn), pd = __expf(v3.y - mn);
      float pe = __expf(v3.z - mn), pf = __expf(v3.w - mn);
      half8 h0, h1;
      h0[0] = (_Float16)p0; h0[1] = (_Float16)p1; h0[2] = (_Float16)p2; h0[3] = (_Float16)p3;
      h0[4] = (_Float16)p4; h0[5] = (_Float16)p5; h0[6] = (_Float16)p6; h0[7] = (_Float16)p7;
      h1[0] = (_Float16)p8; h1[1] = (_Float16)p9; h1[2] = (_Float16)pa; h1[3] = (_Float16)pb;
      h1[4] = (_Float16)pc; h1[5] = (_Float16)pd; h1[6] = (_Float16)pe; h1[7] = (_Float16)pf;
      paf[R][0] = h0; paf[R][1] = h1;
      float ls = ((p0 + p1) + (p2 + p3)) + ((p4 + p5) + (p6 + p7)) +
                 ((p8 + p9) + (pa + pb)) + ((pc + pd) + (pe + pf));
      ls += __shfl_xor(ls, 16);
      ls += __shfl_xor(ls, 32);
      lr[R] = lr[R] * sc[R] + ls;
      mr[R] = mn;
    }

    // ---- E: rescale + PV (wave w owns d-cols 32w..32w+31) ----
#pragma unroll
    for (int e = 0; e < 4; ++e) {
      float r0 = __shfl(sc[0], 4 * l4 + e);
      float r1 = __shfl(sc[1], 4 * l4 + e);
      pv[0][0][e] *= r0; pv[0][1][e] *= r0;
      pv[1][0][e] *= r1; pv[1][1][e] *= r1;
    }
#pragma unroll
    for (int ks = 0; ks < 2; ++ks) {
      half8 vb[2];
#pragma unroll
      for (int C = 0; C < 2; ++C) {
        int d = 32 * w + 16 * C + l15;
        int ch = ks * 4 + l4;
        vb[C] = *(const half8*)((char*)KjT + (size_t)(d * 8 + (ch ^ (d & 7))) * 16);
      }
#pragma unroll
      for (int R = 0; R < 2; ++R)
#pragma unroll
        for (int C = 0; C < 2; ++C)
          pv[R][C] = __builtin_amdgcn_mfma_f32_16x16x32_f16(paf[R][ks], vb[C], pv[R][C], 0, 0, 0);
    }
    __syncthreads();  // B3: all LDS reads of Kj/KjT/sel done

    // ---- F: write staged tile + re-init sel ----
    if (jt < 7) {
#pragma unroll
      for (int p = 0; p < 4; ++p) {
        int cid = p * 256 + tid;
        int j = cid >> 4, cl = cid & 15;
        *(uint4*)((char*)Kj + (size_t)(j * 16 + (cl ^ (j & 15))) * 16) = kreg[p];
      }
#pragma unroll
      for (int p = 0; p < 4; ++p) {
        int cid = p * 256 + tid;
        int d = cid >> 3, cl = cid & 7;
        *(uint4*)((char*)KjT + (size_t)(d * 8 + (cl ^ (d & 7))) * 16) = treg[p];
      }
      float4 mv = make_float4(MASKV, MASKV, MASKV, MASKV);
      *(float4*)(sel + tid * 8) = mv;
      *(float4*)(sel + tid * 8 + 4) = mv;
      __syncthreads();  // B4: staged tile visible
    }
  }

  // epilogue
#pragma unroll
  for (int R = 0; R < 2; ++R) {
#pragma unroll
    for (int e = 0; e < 4; ++e) {
      int r = 16 * R + 4 * l4 + e;
      float lv = (R == 0) ? __shfl(lr[0], 4 * l4 + e) : __shfl(lr[1], 4 * l4 + e);
      float inv = 1.0f / lv;
#pragma unroll
      for (int C = 0; C < 2; ++C) {
        int d = 32 * w + 16 * C + l15;
        out[((size_t)b * 512 + i0 + r) * 128 + d] = pv[R][C][e] * inv;
      }
    }
  }
}

extern "C" void kernel_launch(void* const* d_in, const int* in_sizes, int n_in,
                              void* d_out, int out_size, void* d_ws, size_t ws_size,
                              hipStream_t stream) {
  const float* hl = (const float*)d_in[0];
  const float* ht = (const float*)d_in[1];
  const float* ie = (const float*)d_in[2];
  const float* h  = (const float*)d_in[3];
  const int* adj  = (const int*)d_in[4];
  const float* wd = (const float*)d_in[5];
  const float* a0 = (const float*)d_in[6];
  const float* a1 = (const float*)d_in[7];
  const float* a2 = (const float*)d_in[8];
  const float* a3 = (const float*)d_in[9];

  // ws layout (~24.6 MB)
  float* hds = (float*)d_ws;                               // 32 KB
  float* s   = (float*)((char*)d_ws + 32768);              // [4][64][512] = 512 KB
  u16* h16   = (u16*)((char*)d_ws + 557056);               // 8 MB
  u16* h16T  = (u16*)((char*)d_ws + 8945664);              // 8 MB
  u64* msk   = (u64*)((char*)d_ws + 17334272);             // 8 MB
  float* o   = (float*)d_out;

  k_hds<<<64, 128, 0, stream>>>(hl, ht, ie, wd, hds);
  k_mask<<<8192, 256, 0, stream>>>(adj, msk);
  k_prep<<<512, 256, 0, stream>>>(h, hds, a0, a1, a2, a3, s, h16, h16T);
  k_attn<<<1024, 256, 0, stream>>>(h, h16, h16T, s, msk, a0, a1, a2, a3, o);
}

// Round 3
// 219.451 us; speedup vs baseline: 1.4112x; 1.4112x over previous
//
#include <hip/hip_runtime.h>
#include <hip/hip_bf16.h>
#include <hip/hip_fp16.h>

typedef _Float16 half8 __attribute__((ext_vector_type(8)));
typedef float floatx4 __attribute__((ext_vector_type(4)));
typedef unsigned short u16;
typedef unsigned int u32;
typedef unsigned long long u64;

#define LEAKY 0.2f
#define MASKV -9.0e15f

// ---------------- Kernel A: h_ds[b][d] = (mean of 150 rows) @ wd ----------------
__global__ __launch_bounds__(128) void k_hds(const float* __restrict__ hl,
                                             const float* __restrict__ ht,
                                             const float* __restrict__ ie,
                                             const float* __restrict__ wd,
                                             float* __restrict__ hds) {
  int b = blockIdx.x, d = threadIdx.x;
  const size_t base = (size_t)b * 50 * 128 + d;
  float acc = 0.f;
  for (int l2 = 0; l2 < 50; ++l2) {
    size_t o = base + (size_t)l2 * 128;
    acc += hl[o] + ht[o] + ie[o];
  }
  __shared__ float ml[128];
  ml[d] = acc * (1.0f / 150.0f);
  __syncthreads();
  float o = 0.f;
  for (int k = 0; k < 128; ++k) o = fmaf(ml[k], wd[k * 128 + d], o);
  hds[b * 128 + d] = o;
}

// ---------------- Kernel B: s[w][b][i], h16[b][i][d], h16T[b][d][i] ----------------
__global__ __launch_bounds__(256) void k_prep(const float* __restrict__ h,
                                              const float* __restrict__ hds,
                                              const float* __restrict__ a0,
                                              const float* __restrict__ a1,
                                              const float* __restrict__ a2,
                                              const float* __restrict__ a3,
                                              float* __restrict__ s,
                                              u16* __restrict__ h16,
                                              u16* __restrict__ h16T) {
  int b = blockIdx.x >> 3, i0 = (blockIdx.x & 7) * 64;
  int tid = threadIdx.x, w = tid >> 6, l = tid & 63;
  __shared__ u16 tile[64][130];  // +2 pad: conflict-free column reads
  int d0 = 2 * l;
  float2 hd2 = *(const float2*)(hds + b * 128 + d0);
  float2 av0 = *(const float2*)(a0 + d0);
  float2 av1 = *(const float2*)(a1 + d0);
  float2 av2 = *(const float2*)(a2 + d0);
  float2 av3 = *(const float2*)(a3 + d0);
  for (int rr = 0; rr < 16; ++rr) {
    int il = rr * 4 + w;
    size_t row = (size_t)b * 512 + i0 + il;
    float2 hv = *(const float2*)(h + row * 128 + d0);
    _Float16 f0 = (_Float16)hv.x, f1 = (_Float16)hv.y;
    u16 u0 = __builtin_bit_cast(u16, f0), u1 = __builtin_bit_cast(u16, f1);
    tile[il][d0] = u0;
    tile[il][d0 + 1] = u1;
    *(u32*)(h16 + row * 128 + d0) = (u32)u0 | ((u32)u1 << 16);
    float t0 = hv.x * hd2.x, t1 = hv.y * hd2.y;
    float p0 = t0 * av0.x + t1 * av0.y;
    float p1 = t0 * av1.x + t1 * av1.y;
    float p2 = t0 * av2.x + t1 * av2.y;
    float p3 = t0 * av3.x + t1 * av3.y;
    for (int off = 32; off >= 1; off >>= 1) {
      p0 += __shfl_xor(p0, off);
      p1 += __shfl_xor(p1, off);
      p2 += __shfl_xor(p2, off);
      p3 += __shfl_xor(p3, off);
    }
    if (l < 4) {
      float pw = (l == 0) ? p0 : (l == 1) ? p1 : (l == 2) ? p2 : p3;
      s[((size_t)l * 64 + b) * 512 + i0 + il] = pw;
    }
  }
  __syncthreads();
  int d = tid >> 1, hf = tid & 1;
  u32 wds[16];
#pragma unroll
  for (int k = 0; k < 16; ++k) {
    u32 lo = tile[32 * hf + 2 * k][d];
    u32 hi = tile[32 * hf + 2 * k + 1][d];
    wds[k] = lo | (hi << 16);
  }
  uint4* dst = (uint4*)(h16T + ((size_t)b * 128 + d) * 512 + i0 + 32 * hf);
  dst[0] = make_uint4(wds[0], wds[1], wds[2], wds[3]);
  dst[1] = make_uint4(wds[4], wds[5], wds[6], wds[7]);
  dst[2] = make_uint4(wds[8], wds[9], wds[10], wds[11]);
  dst[3] = make_uint4(wds[12], wds[13], wds[14], wds[15]);
}

// ---------------- Kernel C: fused mask-build + 4-head QK + select + softmax + PV ----------------
__global__ __launch_bounds__(256) void k_attn(const float* __restrict__ h,
                                              const u16* __restrict__ h16,
                                              const u16* __restrict__ h16T,
                                              const float* __restrict__ s,
                                              const int* __restrict__ adj,
                                              const float* __restrict__ a0,
                                              const float* __restrict__ a1,
                                              const float* __restrict__ a2,
                                              const float* __restrict__ a3,
                                              float* __restrict__ out) {
  int bid = blockIdx.x;
  int wg = (bid & 7) * 128 + (bid >> 3);  // XCD swizzle: same-b tiles share an XCD
  int b = wg >> 4, i0 = (wg & 15) * 32;
  int tid = threadIdx.x, w = tid >> 6, l = tid & 63;
  int l15 = l & 15, l4 = l >> 4;

  __shared__ u16 KjL[2][64 * 128];   // [j][d] f16, 16B-chunk XOR swizzled (cs = cl ^ (j&15))
  __shared__ u16 KTL[2][128 * 64];   // [d][j] f16, swizzled (cs = cl ^ (d&7))
  __shared__ float sel[32 * 64];     // merged logits, chunk swizzle c4 ^ (r&15)
  __shared__ u64 msk[4][32][8];      // per-head row masks for this i-tile

  const size_t hb16 = (size_t)b * 512 * 128;
  const size_t hTb = (size_t)b * 128 * 512;

  // ---- async DMA staging: LDS dest linear, source pre-swizzled (inverse XOR) ----
  auto stage = [&](int jt, int p) {
    const int j0n = jt * 64;
    u16* KB = &KjL[p][0];
    u16* TB = &KTL[p][0];
#pragma unroll
    for (int i = 0; i < 4; ++i) {
      int q = (4 * w + i) * 64 + l;  // chunk id [0,1024)
      int j = q >> 4, cs = q & 15;
      int cl = cs ^ (j & 15);
      const u16* g = h16 + hb16 + (size_t)(j0n + j) * 128 + cl * 8;
      __builtin_amdgcn_global_load_lds(
          (const __attribute__((address_space(1))) unsigned int*)g,
          (__attribute__((address_space(3))) unsigned int*)(KB + (4 * w + i) * 512),
          16, 0, 0);
    }
#pragma unroll
    for (int i = 0; i < 4; ++i) {
      int q = (4 * w + i) * 64 + l;
      int d = q >> 3, cs = q & 7;
      int cl = cs ^ (d & 7);
      const u16* g = h16T + hTb + (size_t)d * 512 + (j0n + cl * 8);
      __builtin_amdgcn_global_load_lds(
          (const __attribute__((address_space(1))) unsigned int*)g,
          (__attribute__((address_space(3))) unsigned int*)(TB + (4 * w + i) * 512),
          16, 0, 0);
    }
  };

  stage(0, 0);  // tile 0 in flight while we do the prologue

  // ---- build adj bitmasks in LDS: wave w handles rows 8w..8w+7 ----
  {
    const int* ap0 = adj + ((size_t)b * 512 + i0) * 512;
    for (int rr = 0; rr < 8; ++rr) {
      int r = 8 * w + rr;
      const int* ap = ap0 + (size_t)r * 512;
#pragma unroll
      for (int g = 0; g < 8; ++g) {
        int av = ap[g * 64 + l];
        u64 m0 = __ballot(av == 1);
        u64 m1 = __ballot(av == 2);
        u64 m2 = __ballot(av == 3);
        u64 m3 = __ballot(av == 4);
        if (l == 0) {
          msk[0][r][g] = m0;
          msk[1][r][g] = m1;
          msk[2][r][g] = m2;
          msk[3][r][g] = m3;
        }
      }
    }
  }

  const float* aw = (w == 0) ? a0 : (w == 1) ? a1 : (w == 2) ? a2 : a3;

  // Q fragments (head w): row = l15, k = ks*32 + 8*l4 + e
  half8 qf[2][4];
#pragma unroll
  for (int R = 0; R < 2; ++R) {
    int r = 16 * R + l15;
    const float* hp = h + ((size_t)b * 512 + i0 + r) * 128;
#pragma unroll
    for (int ks = 0; ks < 4; ++ks) {
      int db = ks * 32 + l4 * 8;
      float4 h0 = *(const float4*)(hp + db);
      float4 h1 = *(const float4*)(hp + db + 4);
      float4 A0 = *(const float4*)(aw + db);
      float4 A1 = *(const float4*)(aw + db + 4);
      half8 q;
      q[0] = (_Float16)(h0.x * A0.x); q[1] = (_Float16)(h0.y * A0.y);
      q[2] = (_Float16)(h0.z * A0.z); q[3] = (_Float16)(h0.w * A0.w);
      q[4] = (_Float16)(h1.x * A1.x); q[5] = (_Float16)(h1.y * A1.y);
      q[6] = (_Float16)(h1.z * A1.z); q[7] = (_Float16)(h1.w * A1.w);
      qf[R][ks] = q;
    }
  }
  // s_i (head w), C-frag rows
  float si[2][4];
#pragma unroll
  for (int R = 0; R < 2; ++R)
#pragma unroll
    for (int e = 0; e < 4; ++e)
      si[R][e] = s[((size_t)w * 64 + b) * 512 + i0 + 16 * R + 4 * l4 + e];

  // init sel for iteration 0
  {
    float4 mv = make_float4(MASKV, MASKV, MASKV, MASKV);
    *(float4*)(sel + tid * 8) = mv;
    *(float4*)(sel + tid * 8 + 4) = mv;
  }

  float mr[2] = {-__builtin_inff(), -__builtin_inff()};
  float lr[2] = {0.f, 0.f};
  floatx4 pv[2][2];
#pragma unroll
  for (int R = 0; R < 2; ++R)
#pragma unroll
    for (int C = 0; C < 2; ++C) pv[R][C] = (floatx4){0.f, 0.f, 0.f, 0.f};

  for (int jt = 0; jt < 8; ++jt) {
    int p = jt & 1;
    int j0 = jt * 64;

    __syncthreads();  // full drain: tile jt DMA landed (all waves), prior-iter LDS reads done

    if (jt < 7) stage(jt + 1, p ^ 1);  // next tile in flight under this iteration's compute

    // mask words + s_j for this tile
    u64 mw[8];
#pragma unroll
    for (int k = 0; k < 8; ++k) {
      int r = 16 * (k >> 2) + 4 * l4 + (k & 3);
      mw[k] = msk[w][r][jt];
    }
    float sj[4];
#pragma unroll
    for (int C = 0; C < 4; ++C)
      sj[C] = s[((size_t)w * 64 + b) * 512 + j0 + 16 * C + l15];

    // ---- QK^T (head w) ----
    floatx4 qk[2][4];
#pragma unroll
    for (int R = 0; R < 2; ++R)
#pragma unroll
      for (int C = 0; C < 4; ++C) qk[R][C] = (floatx4){0.f, 0.f, 0.f, 0.f};
#pragma unroll
    for (int ks = 0; ks < 4; ++ks) {
      half8 bf[4];
#pragma unroll
      for (int C = 0; C < 4; ++C) {
        int j = 16 * C + l15;
        int ch = ks * 4 + l4;
        bf[C] = *(const half8*)((char*)&KjL[p][0] + (size_t)(j * 16 + (ch ^ (j & 15))) * 16);
      }
#pragma unroll
      for (int R = 0; R < 2; ++R)
#pragma unroll
        for (int C = 0; C < 4; ++C)
          qk[R][C] = __builtin_amdgcn_mfma_f32_16x16x32_f16(qf[R][ks], bf[C], qk[R][C], 0, 0, 0);
    }
    // ---- select via bitmask, write merged logits ----
#pragma unroll
    for (int C = 0; C < 4; ++C) {
#pragma unroll
      for (int R = 0; R < 2; ++R) {
#pragma unroll
        for (int e = 0; e < 4; ++e) {
          int k = R * 4 + e;
          u32 hlf = (C < 2) ? (u32)mw[k] : (u32)(mw[k] >> 32);
          if ((hlf >> (16 * (C & 1) + l15)) & 1) {
            float x = qk[R][C][e] + si[R][e] + sj[C];
            x = (x > 0.f) ? x : LEAKY * x;
            int r = 16 * R + 4 * l4 + e;
            int sw = (4 * C + (l15 >> 2)) ^ (r & 15);
            sel[r * 64 + sw * 4 + (l15 & 3)] = x;
          }
        }
      }
    }

    // mid barrier: sel complete — LDS-only drain, next-tile DMA stays in flight
    asm volatile("s_waitcnt lgkmcnt(0)" ::: "memory");
    __builtin_amdgcn_s_barrier();
    __builtin_amdgcn_sched_barrier(0);

    // ---- in-register online softmax (per-wave, redundant across waves) ----
    float sc[2];
    half8 paf[2][2];
#pragma unroll
    for (int R = 0; R < 2; ++R) {
      int r = 16 * R + l15;
      int swa0 = (2 * l4) ^ l15;
      int swa1 = (8 + 2 * l4) ^ l15;
      float4 v0 = *(float4*)(sel + r * 64 + swa0 * 4);
      float4 v1 = *(float4*)(sel + r * 64 + (swa0 ^ 1) * 4);
      float4 v2 = *(float4*)(sel + r * 64 + swa1 * 4);
      float4 v3 = *(float4*)(sel + r * 64 + (swa1 ^ 1) * 4);
      float tmax = fmaxf(
          fmaxf(fmaxf(fmaxf(v0.x, v0.y), fmaxf(v0.z, v0.w)),
                fmaxf(fmaxf(v1.x, v1.y), fmaxf(v1.z, v1.w))),
          fmaxf(fmaxf(fmaxf(v2.x, v2.y), fmaxf(v2.z, v2.w)),
                fmaxf(fmaxf(v3.x, v3.y), fmaxf(v3.z, v3.w))));
      tmax = fmaxf(tmax, __shfl_xor(tmax, 16));
      tmax = fmaxf(tmax, __shfl_xor(tmax, 32));
      float mo = mr[R], mn = fmaxf(mo, tmax);
      sc[R] = __expf(mo - mn);
      float p0 = __expf(v0.x - mn), p1 = __expf(v0.y - mn);
      float p2 = __expf(v0.z - mn), p3 = __expf(v0.w - mn);
      float p4 = __expf(v1.x - mn), p5 = __expf(v1.y - mn);
      float p6 = __expf(v1.z - mn), p7 = __expf(v1.w - mn);
      float p8 = __expf(v2.x - mn), p9 = __expf(v2.y - mn);
      float pa = __expf(v2.z - mn), pb = __expf(v2.w - mn);
      float pc = __expf(v3.x - mn), pd = __expf(v3.y - mn);
      float pe = __expf(v3.z - mn), pf = __expf(v3.w - mn);
      half8 h0, h1;
      h0[0] = (_Float16)p0; h0[1] = (_Float16)p1; h0[2] = (_Float16)p2; h0[3] = (_Float16)p3;
      h0[4] = (_Float16)p4; h0[5] = (_Float16)p5; h0[6] = (_Float16)p6; h0[7] = (_Float16)p7;
      h1[0] = (_Float16)p8; h1[1] = (_Float16)p9; h1[2] = (_Float16)pa; h1[3] = (_Float16)pb;
      h1[4] = (_Float16)pc; h1[5] = (_Float16)pd; h1[6] = (_Float16)pe; h1[7] = (_Float16)pf;
      paf[R][0] = h0; paf[R][1] = h1;
      float ls = ((p0 + p1) + (p2 + p3)) + ((p4 + p5) + (p6 + p7)) +
                 ((p8 + p9) + (pa + pb)) + ((pc + pd) + (pe + pf));
      ls += __shfl_xor(ls, 16);
      ls += __shfl_xor(ls, 32);
      lr[R] = lr[R] * sc[R] + ls;
      mr[R] = mn;
    }
    // rescale accumulators (register-only)
#pragma unroll
    for (int e = 0; e < 4; ++e) {
      float r0 = __shfl(sc[0], 4 * l4 + e);
      float r1 = __shfl(sc[1], 4 * l4 + e);
      pv[0][0][e] *= r0; pv[0][1][e] *= r0;
      pv[1][0][e] *= r1; pv[1][1][e] *= r1;
    }

    // b3: all sel reads done -> safe to re-init (plain barrier, nothing to drain)
    __builtin_amdgcn_s_barrier();
    __builtin_amdgcn_sched_barrier(0);
    asm volatile("" ::: "memory");

    if (jt < 7) {
      float4 mv = make_float4(MASKV, MASKV, MASKV, MASKV);
      *(float4*)(sel + tid * 8) = mv;
      *(float4*)(sel + tid * 8 + 4) = mv;
    }

    // ---- PV (wave w owns d-cols 32w..32w+31) ----
#pragma unroll
    for (int ks = 0; ks < 2; ++ks) {
      half8 vb[2];
#pragma unroll
      for (int C = 0; C < 2; ++C) {
        int d = 32 * w + 16 * C + l15;
        int ch = ks * 4 + l4;
        vb[C] = *(const half8*)((char*)&KTL[p][0] + (size_t)(d * 8 + (ch ^ (d & 7))) * 16);
      }
#pragma unroll
      for (int R = 0; R < 2; ++R)
#pragma unroll
        for (int C = 0; C < 2; ++C)
          pv[R][C] = __builtin_amdgcn_mfma_f32_16x16x32_f16(paf[R][ks], vb[C], pv[R][C], 0, 0, 0);
    }
  }

  // epilogue
#pragma unroll
  for (int R = 0; R < 2; ++R) {
#pragma unroll
    for (int e = 0; e < 4; ++e) {
      int r = 16 * R + 4 * l4 + e;
      float lv = (R == 0) ? __shfl(lr[0], 4 * l4 + e) : __shfl(lr[1], 4 * l4 + e);
      float inv = 1.0f / lv;
#pragma unroll
      for (int C = 0; C < 2; ++C) {
        int d = 32 * w + 16 * C + l15;
        out[((size_t)b * 512 + i0 + r) * 128 + d] = pv[R][C][e] * inv;
      }
    }
  }
}

extern "C" void kernel_launch(void* const* d_in, const int* in_sizes, int n_in,
                              void* d_out, int out_size, void* d_ws, size_t ws_size,
                              hipStream_t stream) {
  const float* hl = (const float*)d_in[0];
  const float* ht = (const float*)d_in[1];
  const float* ie = (const float*)d_in[2];
  const float* h  = (const float*)d_in[3];
  const int* adj  = (const int*)d_in[4];
  const float* wd = (const float*)d_in[5];
  const float* a0 = (const float*)d_in[6];
  const float* a1 = (const float*)d_in[7];
  const float* a2 = (const float*)d_in[8];
  const float* a3 = (const float*)d_in[9];

  // ws layout (~16.6 MB)
  float* hds = (float*)d_ws;                   // 32 KB
  float* s   = (float*)((char*)d_ws + 32768);  // [4][64][512] = 512 KB
  u16* h16   = (u16*)((char*)d_ws + 557056);   // 8 MB
  u16* h16T  = (u16*)((char*)d_ws + 8945664);  // 8 MB
  float* o   = (float*)d_out;

  k_hds<<<64, 128, 0, stream>>>(hl, ht, ie, wd, hds);
  k_prep<<<512, 256, 0, stream>>>(h, hds, a0, a1, a2, a3, s, h16, h16T);
  k_attn<<<1024, 256, 0, stream>>>(h, h16, h16T, s, adj, a0, a1, a2, a3, o);
}

// Round 5
// 176.312 us; speedup vs baseline: 1.7565x; 1.2447x over previous
//
#include <hip/hip_runtime.h>
#include <hip/hip_bf16.h>
#include <hip/hip_fp16.h>

typedef _Float16 half8 __attribute__((ext_vector_type(8)));
typedef float floatx4 __attribute__((ext_vector_type(4)));
typedef unsigned short u16;
typedef unsigned int u32;
typedef unsigned long long u64;

#define LEAKY 0.2f
#define MASKV -9.0e15f

// ---------------- Kernel A: h_ds[b][d] = (mean of 150 rows) @ wd ----------------
__global__ __launch_bounds__(128) void k_hds(const float* __restrict__ hl,
                                             const float* __restrict__ ht,
                                             const float* __restrict__ ie,
                                             const float* __restrict__ wd,
                                             float* __restrict__ hds) {
  int b = blockIdx.x, d = threadIdx.x;
  const size_t base = (size_t)b * 50 * 128 + d;
  float acc = 0.f;
  for (int l2 = 0; l2 < 50; ++l2) {
    size_t o = base + (size_t)l2 * 128;
    acc += hl[o] + ht[o] + ie[o];
  }
  __shared__ float ml[128];
  ml[d] = acc * (1.0f / 150.0f);
  __syncthreads();
  float o = 0.f;
  for (int k = 0; k < 128; ++k) o = fmaf(ml[k], wd[k * 128 + d], o);
  hds[b * 128 + d] = o;
}

// ---------------- Kernel B: s[w][b][i], h16[b][i][d], h16T[b][d][i] ----------------
__global__ __launch_bounds__(256) void k_prep(const float* __restrict__ h,
                                              const float* __restrict__ hds,
                                              const float* __restrict__ a0,
                                              const float* __restrict__ a1,
                                              const float* __restrict__ a2,
                                              const float* __restrict__ a3,
                                              float* __restrict__ s,
                                              u16* __restrict__ h16,
                                              u16* __restrict__ h16T) {
  int b = blockIdx.x >> 3, i0 = (blockIdx.x & 7) * 64;
  int tid = threadIdx.x, w = tid >> 6, l = tid & 63;
  __shared__ u16 tile[64][130];
  int d0 = 2 * l;
  float2 hd2 = *(const float2*)(hds + b * 128 + d0);
  float2 av0 = *(const float2*)(a0 + d0);
  float2 av1 = *(const float2*)(a1 + d0);
  float2 av2 = *(const float2*)(a2 + d0);
  float2 av3 = *(const float2*)(a3 + d0);
  for (int rr = 0; rr < 16; ++rr) {
    int il = rr * 4 + w;
    size_t row = (size_t)b * 512 + i0 + il;
    float2 hv = *(const float2*)(h + row * 128 + d0);
    _Float16 f0 = (_Float16)hv.x, f1 = (_Float16)hv.y;
    u16 u0 = __builtin_bit_cast(u16, f0), u1 = __builtin_bit_cast(u16, f1);
    tile[il][d0] = u0;
    tile[il][d0 + 1] = u1;
    *(u32*)(h16 + row * 128 + d0) = (u32)u0 | ((u32)u1 << 16);
    float t0 = hv.x * hd2.x, t1 = hv.y * hd2.y;
    float p0 = t0 * av0.x + t1 * av0.y;
    float p1 = t0 * av1.x + t1 * av1.y;
    float p2 = t0 * av2.x + t1 * av2.y;
    float p3 = t0 * av3.x + t1 * av3.y;
    for (int off = 32; off >= 1; off >>= 1) {
      p0 += __shfl_xor(p0, off);
      p1 += __shfl_xor(p1, off);
      p2 += __shfl_xor(p2, off);
      p3 += __shfl_xor(p3, off);
    }
    if (l < 4) {
      float pw = (l == 0) ? p0 : (l == 1) ? p1 : (l == 2) ? p2 : p3;
      s[((size_t)l * 64 + b) * 512 + i0 + il] = pw;
    }
  }
  __syncthreads();
  int d = tid >> 1, hf = tid & 1;
  u32 wds[16];
#pragma unroll
  for (int k = 0; k < 16; ++k) {
    u32 lo = tile[32 * hf + 2 * k][d];
    u32 hi = tile[32 * hf + 2 * k + 1][d];
    wds[k] = lo | (hi << 16);
  }
  uint4* dst = (uint4*)(h16T + ((size_t)b * 128 + d) * 512 + i0 + 32 * hf);
  dst[0] = make_uint4(wds[0], wds[1], wds[2], wds[3]);
  dst[1] = make_uint4(wds[4], wds[5], wds[6], wds[7]);
  dst[2] = make_uint4(wds[8], wds[9], wds[10], wds[11]);
  dst[3] = make_uint4(wds[12], wds[13], wds[14], wds[15]);
}

// ---------------- Kernel B2: adj -> per-head bitmasks ----------------
__global__ __launch_bounds__(256) void k_mask(const int* __restrict__ adj,
                                              u64* __restrict__ mask) {
  int row = blockIdx.x * 4 + (threadIdx.x >> 6);
  int l = threadIdx.x & 63;
  int b = row >> 9, i = row & 511;
  const int* ap = adj + (size_t)row * 512;
#pragma unroll
  for (int g = 0; g < 8; ++g) {
    int av = ap[g * 64 + l];
    u64 m0 = __ballot(av == 1);
    u64 m1 = __ballot(av == 2);
    u64 m2 = __ballot(av == 3);
    u64 m3 = __ballot(av == 4);
    if (l == 0) mask[(((size_t)b * 4 + 0) * 512 + i) * 8 + g] = m0;
    if (l == 1) mask[(((size_t)b * 4 + 1) * 512 + i) * 8 + g] = m1;
    if (l == 2) mask[(((size_t)b * 4 + 2) * 512 + i) * 8 + g] = m2;
    if (l == 3) mask[(((size_t)b * 4 + 3) * 512 + i) * 8 + g] = m3;
  }
}

// ---------------- Kernel C: independent-wave fused attention ----------------
// Block = 4 waves. Wave = (16-row i-tile, j-half, all 4 heads). No barriers in j-loop.
__global__ __launch_bounds__(256) void k_attn(const u16* __restrict__ h16,
                                              const u16* __restrict__ h16T,
                                              const float* __restrict__ s,
                                              const u64* __restrict__ mask,
                                              const float* __restrict__ a0,
                                              const float* __restrict__ a1,
                                              const float* __restrict__ a2,
                                              const float* __restrict__ a3,
                                              float* __restrict__ out) {
  int bid = blockIdx.x;
  int wg = (bid & 7) * 128 + (bid >> 3);  // XCD swizzle: b in [8k,8k+8) on XCD k
  int b = wg >> 4, r32 = (wg & 15) * 32;
  int tid = threadIdx.x, w = tid >> 6, l = tid & 63;
  int l15 = l & 15, l4 = l >> 4;
  int pair = w >> 1, jh = w & 1;
  int i0r = r32 + pair * 16;  // this wave's 16 rows

  __shared__ u16 a16[4][128];       // a vectors, f16
  __shared__ u16 pbuf[4][16][72];   // per-wave P relayout (pitch 72 -> 2-way max)
  __shared__ float mrg[2][16][132]; // pair-merge pv
  __shared__ float mml[2][16][2];   // pair-merge m,l

  if (tid < 128) {
    a16[0][tid] = __builtin_bit_cast(u16, (_Float16)a0[tid]);
    a16[1][tid] = __builtin_bit_cast(u16, (_Float16)a1[tid]);
    a16[2][tid] = __builtin_bit_cast(u16, (_Float16)a2[tid]);
    a16[3][tid] = __builtin_bit_cast(u16, (_Float16)a3[tid]);
  }
  __syncthreads();

  const size_t hb16 = (size_t)b * 512 * 128;
  const size_t hTb = (size_t)b * 128 * 512;

  // A-side h fragments (iteration-invariant): row = l15, k = ks*32+8*l4+e
  half8 hf[4];
#pragma unroll
  for (int ks = 0; ks < 4; ++ks)
    hf[ks] = *(const half8*)(h16 + hb16 + (size_t)(i0r + l15) * 128 + ks * 32 + 8 * l4);

  // s_i per head for this wave's C-frag rows (r = 4*l4+e)
  float si[4][4];
#pragma unroll
  for (int h = 0; h < 4; ++h)
#pragma unroll
    for (int e = 0; e < 4; ++e)
      si[h][e] = s[((size_t)h * 64 + b) * 512 + i0r + 4 * l4 + e];

  float m[4], lsum[4];
#pragma unroll
  for (int e = 0; e < 4; ++e) { m[e] = MASKV; lsum[e] = 0.f; }
  floatx4 pv[8];
#pragma unroll
  for (int dt = 0; dt < 8; ++dt) pv[dt] = (floatx4){0.f, 0.f, 0.f, 0.f};

  for (int t = 0; t < 4; ++t) {
    int j0 = jh * 256 + t * 64;
    int jw = jh * 4 + t;

    float x[4][4];
#pragma unroll
    for (int C = 0; C < 4; ++C)
#pragma unroll
      for (int e = 0; e < 4; ++e) x[C][e] = MASKV;

#pragma unroll
    for (int p2 = 0; p2 < 2; ++p2) {
      int h0 = 2 * p2, h1 = 2 * p2 + 1;
      // masks + s_j for these two heads
      u64 mk0[4], mk1[4];
#pragma unroll
      for (int e = 0; e < 4; ++e) {
        mk0[e] = mask[(((size_t)b * 4 + h0) * 512 + i0r + 4 * l4 + e) * 8 + jw];
        mk1[e] = mask[(((size_t)b * 4 + h1) * 512 + i0r + 4 * l4 + e) * 8 + jw];
      }
      float sj0[4], sj1[4];
#pragma unroll
      for (int C = 0; C < 4; ++C) {
        sj0[C] = s[((size_t)h0 * 64 + b) * 512 + j0 + 16 * C + l15];
        sj1[C] = s[((size_t)h1 * 64 + b) * 512 + j0 + 16 * C + l15];
      }
      // QK^T for heads h0,h1
      floatx4 qk0[4], qk1[4];
#pragma unroll
      for (int C = 0; C < 4; ++C) {
        qk0[C] = (floatx4){0.f, 0.f, 0.f, 0.f};
        qk1[C] = (floatx4){0.f, 0.f, 0.f, 0.f};
      }
#pragma unroll
      for (int ks = 0; ks < 4; ++ks) {
        half8 kf[4];
#pragma unroll
        for (int C = 0; C < 4; ++C)
          kf[C] = *(const half8*)(h16 + hb16 + (size_t)(j0 + 16 * C + l15) * 128 + ks * 32 + 8 * l4);
        half8 af0 = *(const half8*)&a16[h0][ks * 32 + 8 * l4];
        half8 af1 = *(const half8*)&a16[h1][ks * 32 + 8 * l4];
        half8 q0 = hf[ks] * af0;
        half8 q1 = hf[ks] * af1;
#pragma unroll
        for (int C = 0; C < 4; ++C) {
          qk0[C] = __builtin_amdgcn_mfma_f32_16x16x32_f16(q0, kf[C], qk0[C], 0, 0, 0);
          qk1[C] = __builtin_amdgcn_mfma_f32_16x16x32_f16(q1, kf[C], qk1[C], 0, 0, 0);
        }
      }
      // merge into x via mask bits (at most one head owns each (i,j))
#pragma unroll
      for (int e = 0; e < 4; ++e) {
        u64 sh0 = mk0[e] >> l15;
        u64 sh1 = mk1[e] >> l15;
#pragma unroll
        for (int C = 0; C < 4; ++C) {
          if ((sh0 >> (16 * C)) & 1) {
            float v = qk0[C][e] + si[h0][e] + sj0[C];
            x[C][e] = (v > 0.f) ? v : LEAKY * v;
          }
          if ((sh1 >> (16 * C)) & 1) {
            float v = qk1[C][e] + si[h1][e] + sj1[C];
            x[C][e] = (v > 0.f) ? v : LEAKY * v;
          }
        }
      }
    }

    // ---- online softmax (in-register; rows r = 4*l4+e across 16 l15 lanes) ----
#pragma unroll
    for (int e = 0; e < 4; ++e) {
      float tmax = fmaxf(fmaxf(x[0][e], x[1][e]), fmaxf(x[2][e], x[3][e]));
      tmax = fmaxf(tmax, __shfl_xor(tmax, 1));
      tmax = fmaxf(tmax, __shfl_xor(tmax, 2));
      tmax = fmaxf(tmax, __shfl_xor(tmax, 4));
      tmax = fmaxf(tmax, __shfl_xor(tmax, 8));
      float mn = fmaxf(m[e], tmax);
      float sc = __expf(m[e] - mn);
      float p0 = __expf(x[0][e] - mn);
      float p1 = __expf(x[1][e] - mn);
      float p2 = __expf(x[2][e] - mn);
      float p3 = __expf(x[3][e] - mn);
      float ls = (p0 + p1) + (p2 + p3);
      ls += __shfl_xor(ls, 1);
      ls += __shfl_xor(ls, 2);
      ls += __shfl_xor(ls, 4);
      ls += __shfl_xor(ls, 8);
      lsum[e] = lsum[e] * sc + ls;
      m[e] = mn;
#pragma unroll
      for (int dt = 0; dt < 8; ++dt) pv[dt][e] *= sc;
      int r = 4 * l4 + e;
      pbuf[w][r][0 + l15] = __builtin_bit_cast(u16, (_Float16)p0);
      pbuf[w][r][16 + l15] = __builtin_bit_cast(u16, (_Float16)p1);
      pbuf[w][r][32 + l15] = __builtin_bit_cast(u16, (_Float16)p2);
      pbuf[w][r][48 + l15] = __builtin_bit_cast(u16, (_Float16)p3);
    }

    asm volatile("s_waitcnt lgkmcnt(0)" ::: "memory");
    __builtin_amdgcn_sched_barrier(0);

    // ---- PV: A = P (row=l15), B = V^T from h16T ----
#pragma unroll
    for (int ks2 = 0; ks2 < 2; ++ks2) {
      half8 pa = *(const half8*)((const char*)&pbuf[w][0][0] + l15 * 144 + ks2 * 64 + l4 * 16);
#pragma unroll
      for (int dt = 0; dt < 8; ++dt) {
        half8 vb = *(const half8*)(h16T + hTb + (size_t)(16 * dt + l15) * 512 + j0 + ks2 * 32 + 8 * l4);
        pv[dt] = __builtin_amdgcn_mfma_f32_16x16x32_f16(pa, vb, pv[dt], 0, 0, 0);
      }
    }
  }

  // ---- pair merge (jh=1 publishes, jh=0 merges + writes) ----
  if (jh == 1) {
#pragma unroll
    for (int dt = 0; dt < 8; ++dt)
#pragma unroll
      for (int e = 0; e < 4; ++e)
        mrg[pair][4 * l4 + e][16 * dt + l15] = pv[dt][e];
    if (l15 == 0) {
#pragma unroll
      for (int e = 0; e < 4; ++e) {
        mml[pair][4 * l4 + e][0] = m[e];
        mml[pair][4 * l4 + e][1] = lsum[e];
      }
    }
  }
  __syncthreads();
  if (jh == 0) {
    float s0[4], s1[4];
#pragma unroll
    for (int e = 0; e < 4; ++e) {
      float m1 = mml[pair][4 * l4 + e][0];
      float l1 = mml[pair][4 * l4 + e][1];
      float M = fmaxf(m[e], m1);
      float e0 = __expf(m[e] - M);
      float e1 = __expf(m1 - M);
      float L = lsum[e] * e0 + l1 * e1;
      float inv = 1.0f / L;
      s0[e] = e0 * inv;
      s1[e] = e1 * inv;
    }
#pragma unroll
    for (int dt = 0; dt < 8; ++dt)
#pragma unroll
      for (int e = 0; e < 4; ++e) {
        int r = 4 * l4 + e;
        float o = pv[dt][e] * s0[e] + mrg[pair][r][16 * dt + l15] * s1[e];
        out[((size_t)b * 512 + i0r + r) * 128 + 16 * dt + l15] = o;
      }
  }
}

extern "C" void kernel_launch(void* const* d_in, const int* in_sizes, int n_in,
                              void* d_out, int out_size, void* d_ws, size_t ws_size,
                              hipStream_t stream) {
  const float* hl = (const float*)d_in[0];
  const float* ht = (const float*)d_in[1];
  const float* ie = (const float*)d_in[2];
  const float* h  = (const float*)d_in[3];
  const int* adj  = (const int*)d_in[4];
  const float* wd = (const float*)d_in[5];
  const float* a0 = (const float*)d_in[6];
  const float* a1 = (const float*)d_in[7];
  const float* a2 = (const float*)d_in[8];
  const float* a3 = (const float*)d_in[9];

  // ws layout (~24.6 MB)
  float* hds = (float*)d_ws;                   // 32 KB
  float* s   = (float*)((char*)d_ws + 32768);  // [4][64][512] = 512 KB
  u16* h16   = (u16*)((char*)d_ws + 557056);   // 8 MB
  u16* h16T  = (u16*)((char*)d_ws + 8945664);  // 8 MB
  u64* msk   = (u64*)((char*)d_ws + 17334272); // 8 MB
  float* o   = (float*)d_out;

  k_hds<<<64, 128, 0, stream>>>(hl, ht, ie, wd, hds);
  k_mask<<<8192, 256, 0, stream>>>(adj, msk);
  k_prep<<<512, 256, 0, stream>>>(h, hds, a0, a1, a2, a3, s, h16, h16T);
  k_attn<<<1024, 256, 0, stream>>>(h16, h16T, s, msk, a0, a1, a2, a3, o);
}